// Round 6
// baseline (314.384 us; speedup 1.0000x reference)
//
#include <hip/hip_runtime.h>
#include <stdint.h>

#define HIDDEN 1024
#define INTER  4096
#define ROWS   8192               // 4 * 2048
#define BM     128                // rows per GEMM block
#define BN     128                // cols per GEMM block (1/8 of HIDDEN)
#define NKSTEP 64                 // INTER / 64
#define NBLK   512                // 64 row-tiles x 8 column eighths, 2 blocks/CU
#define BSTEP  65536              // bytes per K-step in Bg (full 1024 cols)

typedef int i32x4 __attribute__((ext_vector_type(4)));

// sign byte: +1 (0x01) for x>=0, -1 (0xFF) for x<0.
__device__ __forceinline__ uint32_t sgn4(float4 v) {
    uint32_t b0 = (v.x < 0.f) ? 0xFFu : 0x01u;
    uint32_t b1 = (v.y < 0.f) ? 0xFFu : 0x01u;
    uint32_t b2 = (v.z < 0.f) ? 0xFFu : 0x01u;
    uint32_t b3 = (v.w < 0.f) ? 0xFFu : 0x01u;
    return b0 | (b1 << 8) | (b2 << 16) | (b3 << 24);
}

// ---------------------------------------------------------------------------
// K1: W [1024][4096] f32 -> Bg frag-major i8 signs + wscale (r2-proven layout):
//   byte(h,k) = (k>>6)*BSTEP + (h>>4)*1024 + ((k&63)>>4)*256 + (h&15)*16 + (k&15)
// A 16-col MFMA B-fragment for K-step t is the contiguous 1 KB at
//   Bg + t*BSTEP + cb*1024, element lane*16.
// ---------------------------------------------------------------------------
__global__ __launch_bounds__(256)
void pack_w_kernel(const float* __restrict__ W, uint8_t* __restrict__ Bg,
                   float* __restrict__ wscale) {
    int h = blockIdx.x;
    int tid = threadIdx.x;
    int lane = tid & 63, wv = tid >> 6;
    const float4* row = (const float4*)(W + (size_t)h * INTER);
    const uint32_t base_h = (uint32_t)(h >> 4) * 1024u + (uint32_t)(h & 15) * 16u;
    float asum = 0.f;
    #pragma unroll
    for (int q = 0; q < 4; ++q) {
        int g = q * 256 + tid;                 // float4 index 0..1023 (coalesced)
        float4 v = row[g];
        asum += fabsf(v.x) + fabsf(v.y) + fabsf(v.z) + fabsf(v.w);
        uint32_t off = (uint32_t)(g >> 4) * (uint32_t)BSTEP + base_h
                     + (uint32_t)((g & 15) >> 2) * 256u + (uint32_t)(g & 3) * 4u;
        *(uint32_t*)(Bg + off) = sgn4(v);
    }
    #pragma unroll
    for (int off = 32; off > 0; off >>= 1) asum += __shfl_down(asum, off);
    __shared__ float red[4];
    if (lane == 0) red[wv] = asum;
    __syncthreads();
    if (tid == 0) wscale[h] = (red[0] + red[1] + red[2] + red[3]) * (1.0f / INTER);
}

// ---------------------------------------------------------------------------
// K2: i8 MFMA GEMM, 512 blocks x 512 thr, BM=128 x BN=128.
//   bid -> (mt = bid&63, ch = bid>>6): all 8 col-blocks of a row-tile (and the
//   2 co-resident blocks per CU, bid and bid+256) land on the same XCD -> hs
//   is HBM-fetched once, L2-shared. B traffic = 512 * 512KB = 256 MB (4x less
//   than r5); per-step Bg working set 64 KB/XCD -> L2-resident.
//   Per wave per step: 8 A-frag ds_read_b128 (conflict-free), 1 B i32x4
//   global->reg prefetch (compiler-counted waits, in flight across barrier),
//   8 MFMA. A tile 8 KB/step double-buffered; one s_barrier per step.
//   Epilogue: y = cw*dot + bias + input -> out (pre-LN). LN finished by K3.
// ---------------------------------------------------------------------------
__global__ __launch_bounds__(512, 4)
void gemm_kernel(const float* __restrict__ hs, const float* __restrict__ input,
                 const float* __restrict__ bias, const float* __restrict__ clipp,
                 float* __restrict__ out, const uint8_t* __restrict__ Bg,
                 const float* __restrict__ wscale) {
    __shared__ alignas(16) uint8_t sA[2 * 8192];   // A sign tiles (frag-major)

    const int tid  = threadIdx.x;
    const int lane = tid & 63;
    const int wave = tid >> 6;
    const int mt   = blockIdx.x & 63;
    const int ch   = blockIdx.x >> 6;              // column eighth (0..7)
    const int m0   = mt * BM;

    // A staging: thread (r = tid>>2, kc = tid&3) owns 16 consecutive K-elems
    // of row r: 4 float4 loads -> 16 sign bytes -> one ds_write_b128 at the
    // frag-major address (r>>4)*1024 + (kc*16 + (r&15))*16.
    const int r  = tid >> 2;
    const int kc = tid & 3;
    const int awofs = (r >> 4) * 1024 + (kc * 16 + (r & 15)) * 16;
    const float* aload = hs + (size_t)(m0 + r) * INTER + kc * 16;

    // B: wave w owns cols ch*128 + w*16 .. +15 -> col-frag cb = ch*8 + w.
    const uint8_t* bbase = Bg + (size_t)(ch * 8 + wave) * 1024 + lane * 16;
    const int fofs = lane * 16;

    i32x4 acc[8];
    #pragma unroll
    for (int rt = 0; rt < 8; ++rt) acc[rt] = (i32x4){0, 0, 0, 0};
    i32x4 Bb0, Bb1;
    float4 av0, av1, av2, av3;

    // ---- prologue: stage A(0), B(0) in regs, A(1) data pending ----
    av0 = *(const float4*)(aload + 0);
    av1 = *(const float4*)(aload + 4);
    av2 = *(const float4*)(aload + 8);
    av3 = *(const float4*)(aload + 12);
    Bb0 = *(const i32x4*)(bbase);
    {
        i32x4 sg = (i32x4){(int)sgn4(av0), (int)sgn4(av1),
                           (int)sgn4(av2), (int)sgn4(av3)};
        *(i32x4*)&sA[awofs] = sg;
    }
    av0 = *(const float4*)(aload + 64);
    av1 = *(const float4*)(aload + 68);
    av2 = *(const float4*)(aload + 72);
    av3 = *(const float4*)(aload + 76);
    asm volatile("s_waitcnt lgkmcnt(0)" ::: "memory");
    __builtin_amdgcn_s_barrier();

// Body T: compute tile T from Bb<BC> + sA[CUR]; prefetch B(T+1) into Bb<BN_>
// (plain register load -> compiler-counted vmcnt, stays in flight across the
// barrier); stage A(T+1) signs; load A(T+2) hs data.
#define BODY(T, CUR, BC, BN_, PFB, PFA) do {                                   \
    const uint8_t* ab_ = sA + (CUR) * 8192;                                    \
    i32x4 af0_ = *(const i32x4*)&ab_[0 * 1024 + fofs];                         \
    i32x4 af1_ = *(const i32x4*)&ab_[1 * 1024 + fofs];                         \
    i32x4 af2_ = *(const i32x4*)&ab_[2 * 1024 + fofs];                         \
    i32x4 af3_ = *(const i32x4*)&ab_[3 * 1024 + fofs];                         \
    i32x4 af4_ = *(const i32x4*)&ab_[4 * 1024 + fofs];                         \
    i32x4 af5_ = *(const i32x4*)&ab_[5 * 1024 + fofs];                         \
    i32x4 af6_ = *(const i32x4*)&ab_[6 * 1024 + fofs];                         \
    i32x4 af7_ = *(const i32x4*)&ab_[7 * 1024 + fofs];                         \
    if (PFB) Bb##BN_ = *(const i32x4*)(bbase + (size_t)((T) + 1) * BSTEP);     \
    __builtin_amdgcn_s_setprio(1);                                             \
    acc[0] = __builtin_amdgcn_mfma_i32_16x16x64_i8(af0_, Bb##BC, acc[0], 0, 0, 0); \
    acc[1] = __builtin_amdgcn_mfma_i32_16x16x64_i8(af1_, Bb##BC, acc[1], 0, 0, 0); \
    acc[2] = __builtin_amdgcn_mfma_i32_16x16x64_i8(af2_, Bb##BC, acc[2], 0, 0, 0); \
    acc[3] = __builtin_amdgcn_mfma_i32_16x16x64_i8(af3_, Bb##BC, acc[3], 0, 0, 0); \
    acc[4] = __builtin_amdgcn_mfma_i32_16x16x64_i8(af4_, Bb##BC, acc[4], 0, 0, 0); \
    acc[5] = __builtin_amdgcn_mfma_i32_16x16x64_i8(af5_, Bb##BC, acc[5], 0, 0, 0); \
    acc[6] = __builtin_amdgcn_mfma_i32_16x16x64_i8(af6_, Bb##BC, acc[6], 0, 0, 0); \
    acc[7] = __builtin_amdgcn_mfma_i32_16x16x64_i8(af7_, Bb##BC, acc[7], 0, 0, 0); \
    __builtin_amdgcn_s_setprio(0);                                             \
    if (PFB) {                                                                 \
        i32x4 sg_ = (i32x4){(int)sgn4(av0), (int)sgn4(av1),                    \
                            (int)sgn4(av2), (int)sgn4(av3)};                   \
        *(i32x4*)&sA[((CUR) ^ 1) * 8192 + awofs] = sg_;                        \
        if (PFA) {                                                             \
            av0 = *(const float4*)(aload + ((T) + 2) * 64 + 0);                \
            av1 = *(const float4*)(aload + ((T) + 2) * 64 + 4);                \
            av2 = *(const float4*)(aload + ((T) + 2) * 64 + 8);                \
            av3 = *(const float4*)(aload + ((T) + 2) * 64 + 12);               \
        }                                                                      \
        asm volatile("s_waitcnt lgkmcnt(0)" ::: "memory");                     \
        __builtin_amdgcn_s_barrier();                                          \
    }                                                                          \
} while (0)

    for (int tt = 0; tt < 31; ++tt) {
        BODY(2 * tt,     0, 0, 1, 1, 1);
        BODY(2 * tt + 1, 1, 1, 0, 1, 1);
    }
    BODY(62, 0, 0, 1, 1, 0);   // prefetch B(63), stage A(63); no A(64) data
    BODY(63, 1, 1, 0, 0, 0);   // final tile
#undef BODY

    // ---- epilogue: y = clip*wscale*dot + bias + input -> out (pre-LN) ----
    const float clip = clipp[0];
    const int l15 = lane & 15;
    const int gcol = ch * BN + wave * 16 + l15;
    const float cw = clip * wscale[gcol];
    const float bi = bias[gcol];
    const int rbase = (lane >> 4) * 4;
    #pragma unroll
    for (int rt = 0; rt < 8; ++rt) {
        #pragma unroll
        for (int rg = 0; rg < 4; ++rg) {
            size_t gidx = (size_t)(m0 + rt * 16 + rbase + rg) * HIDDEN + gcol;
            out[gidx] = fmaf((float)acc[rt][rg], cw, bi + input[gidx]);
        }
    }
}

// ---------------------------------------------------------------------------
// K3: one-pass in-place LayerNorm. One row per wave (1024 f32 = 4 float4/lane).
// ---------------------------------------------------------------------------
__global__ __launch_bounds__(256)
void ln_kernel(float* __restrict__ out, const float* __restrict__ gamma,
               const float* __restrict__ beta) {
    const int lane = threadIdx.x & 63;
    const int wave = threadIdx.x >> 6;
    const int row  = blockIdx.x * 4 + wave;
    float4* rowp = (float4*)(out + (size_t)row * HIDDEN);
    const float4* gm4 = (const float4*)gamma;
    const float4* bt4 = (const float4*)beta;

    float4 v0 = rowp[lane +   0];
    float4 v1 = rowp[lane +  64];
    float4 v2 = rowp[lane + 128];
    float4 v3 = rowp[lane + 192];
    float s = v0.x + v0.y + v0.z + v0.w + v1.x + v1.y + v1.z + v1.w
            + v2.x + v2.y + v2.z + v2.w + v3.x + v3.y + v3.z + v3.w;
    float q = v0.x * v0.x + v0.y * v0.y + v0.z * v0.z + v0.w * v0.w
            + v1.x * v1.x + v1.y * v1.y + v1.z * v1.z + v1.w * v1.w
            + v2.x * v2.x + v2.y * v2.y + v2.z * v2.z + v2.w * v2.w
            + v3.x * v3.x + v3.y * v3.y + v3.z * v3.z + v3.w * v3.w;
    #pragma unroll
    for (int off = 1; off < 64; off <<= 1) {
        s += __shfl_xor(s, off);
        q += __shfl_xor(q, off);
    }
    float mu  = s * (1.0f / HIDDEN);
    float var = fmaf(-mu, mu, q * (1.0f / HIDDEN));
    float rs  = rsqrtf(var + 1e-12f);

    #pragma unroll
    for (int j = 0; j < 4; ++j) {
        int idx = lane + j * 64;
        float4 y = (j == 0) ? v0 : (j == 1) ? v1 : (j == 2) ? v2 : v3;
        float4 g = gm4[idx], b = bt4[idx];
        float4 o;
        o.x = (y.x - mu) * rs * g.x + b.x;
        o.y = (y.y - mu) * rs * g.y + b.y;
        o.z = (y.z - mu) * rs * g.z + b.z;
        o.w = (y.w - mu) * rs * g.w + b.w;
        rowp[idx] = o;
    }
}

// ---------------------------------------------------------------------------
extern "C" void kernel_launch(void* const* d_in, const int* in_sizes, int n_in,
                              void* d_out, int out_size, void* d_ws, size_t ws_size,
                              hipStream_t stream) {
    const float* hs    = (const float*)d_in[0];  // [4,2048,4096]
    const float* inp   = (const float*)d_in[1];  // [4,2048,1024]
    const float* W     = (const float*)d_in[2];  // [1024,4096]
    const float* b     = (const float*)d_in[3];  // [1024]
    const float* clip  = (const float*)d_in[4];  // scalar
    const float* gamma = (const float*)d_in[5];  // [1024]
    const float* beta  = (const float*)d_in[6];  // [1024]
    float* out = (float*)d_out;

    uint8_t* Bg   = (uint8_t*)d_ws;                                 // 4 MB
    float* wscale = (float*)((char*)d_ws + 4u * 1024u * 1024u);     // 4 KB

    pack_w_kernel<<<HIDDEN, 256, 0, stream>>>(W, Bg, wscale);
    gemm_kernel<<<NBLK, 512, 0, stream>>>(hs, inp, b, clip, out, Bg, wscale);
    ln_kernel<<<ROWS / 4, 256, 0, stream>>>(out, gamma, beta);
}